// Round 8
// baseline (100.028 us; speedup 1.0000x reference)
//
#include <hip/hip_runtime.h>

// Chamfer distance, B=8, N=M=8192, D=3, fp32 — fused MFMA formulation.
// fp32 split into f16 hi+lo (x = xh+xl, err ~2^-22). K=16 vectors:
//   A(n): [ah0,ah1,ah2, al0,al1,al2, ah0,ah1,ah2, sqh_n,sql_n, 1,1, 0,0,0]
//   B(m): [bh0,bh1,bh2, bh0,bh1,bh2, bl0,bl1,bl2, 1,1, sqh_m,sql_m, 0,0,0]
// with b = -2c (exact). One v_mfma_f32_32x32x16_f16 = 32x32 tile of
// d(n,m) = sq_n + sq_m - 2<a,c> (+O(1e-5)); each tile feeds BOTH mins.
// R8: 4-wave blocks x4/CU, split lo/hi LDS (conflict-free 16B-stride
// writes), register-pipelined pack (chunk c+1 loads overlap chunk c compute).
// C/D: col=lane&31, row=(reg&3)+8*(reg>>2)+4*(lane>>5)  [HW-verified]
// A/B: row/col=lane&31, k=(lane>>5)*8+j                 [verified R5: absmax 0]

typedef _Float16 half8 __attribute__((ext_vector_type(8)));
typedef float    f16x  __attribute__((ext_vector_type(16)));

constexpr int B      = 8;
constexpr int NPTS   = 8192;
constexpr int TOTAL  = B * NPTS;      // 65536
constexpr int NSTRIP = 128;           // n-rows per block (4 waves * 32)
constexpr int NSTR   = NPTS / NSTRIP; // 64 strips
constexpr int MHALF  = 4096;          // m-range per block
constexpr int CHUNK  = 512;           // m staged in LDS per chunk
constexpr int NCHUNK = MHALF / CHUNK; // 8

// min3 tree: min of 16 C-regs (column-min within a lane), 8 issues.
__device__ __forceinline__ float colmin16(const f16x& a)
{
    float m0 = fminf(fminf(a[0],  a[1]),  a[2]);
    float m1 = fminf(fminf(a[3],  a[4]),  a[5]);
    float m2 = fminf(fminf(a[6],  a[7]),  a[8]);
    float m3 = fminf(fminf(a[9],  a[10]), a[11]);
    float m4 = fminf(fminf(a[12], a[13]), a[14]);
    return fminf(fminf(fminf(m0, m1), m2), fminf(fminf(m3, m4), a[15]));
}

__device__ __forceinline__ void pack_b(const float* __restrict__ cp,
                                       half8& lo, half8& hi)
{
    float cx = cp[0], cy = cp[1], cz = cp[2];
    float x = -2.f * cx, y = -2.f * cy, z = -2.f * cz;
    float sq = fmaf(cx, cx, fmaf(cy, cy, cz * cz));
    _Float16 xh = (_Float16)x, yh = (_Float16)y, zh = (_Float16)z;
    _Float16 xl = (_Float16)(x - (float)xh);
    _Float16 yl = (_Float16)(y - (float)yh);
    _Float16 zl = (_Float16)(z - (float)zh);
    _Float16 sh = (_Float16)sq, sl = (_Float16)(sq - (float)sh);
    lo = half8{xh, yh, zh, xh, yh, zh, xl, yl};
    hi = half8{zl, (_Float16)1.f, (_Float16)1.f, sh, sl,
               (_Float16)0.f, (_Float16)0.f, (_Float16)0.f};
}

// grid (64, 2, 8), block 256 (4 waves x 32 n-rows).
// dist1 (min over m) folded in regs -> d1p[b][mh][n]  (unclamped).
// dist2 (min over n) via LDS atomicMin -> d2p[b][strip][m] (clamped).
__global__ __launch_bounds__(256, 4) void chamfer_mfma(
    const float* __restrict__ in1, const float* __restrict__ in2,
    float* __restrict__ d1p, float* __restrict__ d2p, float* __restrict__ out)
{
    const int b     = blockIdx.z;
    const int strip = blockIdx.x;
    const int mh    = blockIdx.y;
    const int wave  = threadIdx.x >> 6;
    const int lane  = threadIdx.x & 63;
    const int col   = lane & 31;
    const int half  = lane >> 5;

    if ((blockIdx.x | blockIdx.y | blockIdx.z) == 0 && threadIdx.x == 0)
        *out = 0.0f;                   // zero accumulator before reduce runs

    __shared__ _Float16 ldsLo[CHUNK * 8];      // 8 KiB — 16B-stride writes
    __shared__ _Float16 ldsHi[CHUNK * 8];      // 8 KiB
    __shared__ unsigned d2lds[MHALF];          // 16 KiB

    for (int i = threadIdx.x; i < MHALF; i += 256)
        d2lds[i] = 0xFFFFFFFFu;

    // A fragment, packed in-register from raw in1.
    const int nbase = strip * NSTRIP + wave * 32;
    half8 afrag;
    {
        const float* a = in1 + ((size_t)b * NPTS + nbase + col) * 3;
        float x = a[0], y = a[1], z = a[2];
        float sq = fmaf(x, x, fmaf(y, y, z * z));
        _Float16 xh = (_Float16)x, yh = (_Float16)y, zh = (_Float16)z;
        _Float16 xl = (_Float16)(x - (float)xh);
        _Float16 yl = (_Float16)(y - (float)yh);
        _Float16 zl = (_Float16)(z - (float)zh);
        _Float16 sh = (_Float16)sq, sl = (_Float16)(sq - (float)sh);
        half8 lo = {xh, yh, zh, xl, yl, zl, xh, yh};
        half8 hi = {zh, sh, sl, (_Float16)1.f, (_Float16)1.f,
                    (_Float16)0.f, (_Float16)0.f, (_Float16)0.f};
        afrag = half ? hi : lo;
    }

    f16x MN1, zero;
#pragma unroll
    for (int r = 0; r < 16; ++r) { MN1[r] = 1e30f; zero[r] = 0.0f; }

    const float* Craw = in2 + ((size_t)b * NPTS + mh * MHALF) * 3;

    // Pipelined pack: regs hold chunk c's packed points (2 per thread).
    half8 lo0, hi0, lo1, hi1;
    pack_b(Craw + (size_t)threadIdx.x * 3,         lo0, hi0);
    pack_b(Craw + (size_t)(threadIdx.x + 256) * 3, lo1, hi1);

    for (int c = 0; c < NCHUNK; ++c) {
        __syncthreads();               // previous chunk's compute done
        *(half8*)&ldsLo[threadIdx.x * 8]         = lo0;
        *(half8*)&ldsHi[threadIdx.x * 8]         = hi0;
        *(half8*)&ldsLo[(threadIdx.x + 256) * 8] = lo1;
        *(half8*)&ldsHi[(threadIdx.x + 256) * 8] = hi1;
        __syncthreads();

        if (c + 1 < NCHUNK) {          // issue next chunk's loads now;
            const float* n0 = Craw + (size_t)((c + 1) * CHUNK + threadIdx.x) * 3;
            pack_b(n0,                  lo0, hi0);   // latency overlaps compute
            pack_b(n0 + 256 * 3,        lo1, hi1);
        }

        const _Float16* fragBase = half ? ldsHi : ldsLo;
#pragma unroll 2
        for (int t = 0; t < CHUNK / 32; t += 2) {
            half8 bfA = *(const half8*)&fragBase[((t    ) * 32 + col) * 8];
            half8 bfB = *(const half8*)&fragBase[((t + 1) * 32 + col) * 8];
            f16x accA = __builtin_amdgcn_mfma_f32_32x32x16_f16(afrag, bfA, zero, 0, 0, 0);
            f16x accB = __builtin_amdgcn_mfma_f32_32x32x16_f16(afrag, bfB, zero, 0, 0, 0);

            // dist1: per-reg running min across m (v_min3 per reg).
#pragma unroll
            for (int r = 0; r < 16; ++r)
                MN1[r] = fminf(fminf(MN1[r], accA[r]), accB[r]);

            // dist2: column-min of each tile, clamp, LDS atomicMin.
            float vA = fmaxf(colmin16(accA), 0.0f);
            atomicMin(&d2lds[c * CHUNK + t * 32 + col], __float_as_uint(vA));
            float vB = fmaxf(colmin16(accB), 0.0f);
            atomicMin(&d2lds[c * CHUNK + (t + 1) * 32 + col], __float_as_uint(vB));
        }
    }
    __syncthreads();

    float* d2 = d2p + ((size_t)b * NSTR + strip) * NPTS + mh * MHALF;
    for (int i = threadIdx.x; i < MHALF; i += 256)
        d2[i] = __uint_as_float(d2lds[i]);

    // dist1: butterfly min across the 32 cols of each half, lane 0 of each
    // half writes its 16 rows: row = (r&3) + 8*(r>>2) + 4*half.
#pragma unroll
    for (int m = 1; m <= 16; m <<= 1)
#pragma unroll
        for (int r = 0; r < 16; ++r)
            MN1[r] = fminf(MN1[r], __shfl_xor(MN1[r], m, 64));
    if (col == 0) {
        float* d1 = d1p + ((size_t)b * 2 + mh) * NPTS + nbase;
#pragma unroll
        for (int r = 0; r < 16; ++r)
            d1[(r & 3) + 8 * (r >> 2) + 4 * half] = MN1[r];
    }
}

// One thread per 4 m's: fold 64 d2 strip-planes + 2 d1 planes (float4),
// sum, wave-reduce, atomicAdd(out, sum/TOTAL).
__global__ __launch_bounds__(256) void reduce_kernel(
    const float* __restrict__ d1p, const float* __restrict__ d2p,
    float* __restrict__ out)
{
    int g  = blockIdx.x * 256 + threadIdx.x;      // [0, TOTAL/4)
    int b  = g >> 11;
    int mq = g & 2047;                            // float4 index within batch

    const float4* p2 = (const float4*)(d2p + (size_t)b * NSTR * NPTS) + mq;
    float4 v2 = p2[0];
#pragma unroll
    for (int s = 1; s < NSTR; ++s) {
        float4 t = p2[(size_t)s * (NPTS / 4)];
        v2.x = fminf(v2.x, t.x); v2.y = fminf(v2.y, t.y);
        v2.z = fminf(v2.z, t.z); v2.w = fminf(v2.w, t.w);
    }
    float4 a0 = ((const float4*)(d1p + ((size_t)b * 2 + 0) * NPTS))[mq];
    float4 a1 = ((const float4*)(d1p + ((size_t)b * 2 + 1) * NPTS))[mq];
    float v = fmaxf(fminf(a0.x, a1.x), 0.0f) + fmaxf(fminf(a0.y, a1.y), 0.0f)
            + fmaxf(fminf(a0.z, a1.z), 0.0f) + fmaxf(fminf(a0.w, a1.w), 0.0f)
            + v2.x + v2.y + v2.z + v2.w;

#pragma unroll
    for (int off = 32; off; off >>= 1)
        v += __shfl_down(v, off, 64);
    __shared__ float wsum[4];
    int lane = threadIdx.x & 63, w = threadIdx.x >> 6;
    if (lane == 0) wsum[w] = v;
    __syncthreads();
    if (threadIdx.x == 0)
        atomicAdd(out, (wsum[0] + wsum[1] + wsum[2] + wsum[3]) *
                           (1.0f / (float)TOTAL));
}

extern "C" void kernel_launch(void* const* d_in, const int* in_sizes, int n_in,
                              void* d_out, int out_size, void* d_ws, size_t ws_size,
                              hipStream_t stream)
{
    const float* in1 = (const float*)d_in[0];
    const float* in2 = (const float*)d_in[1];
    float* out = (float*)d_out;

    char* ws = (char*)d_ws;
    float* d1p = (float*)ws;                              // 2*TOTAL*4 = 512 KiB
    float* d2p = (float*)(ws + (size_t)2 * TOTAL * 4);    // 64*TOTAL*4 = 16 MiB

    chamfer_mfma<<<dim3(NPTS / NSTRIP, 2, B), 256, 0, stream>>>(
        in1, in2, d1p, d2p, out);
    reduce_kernel<<<TOTAL / 1024, 256, 0, stream>>>(d1p, d2p, out);
}